// Round 1
// baseline (4512.281 us; speedup 1.0000x reference)
//
#include <hip/hip_runtime.h>

typedef unsigned short u16;
typedef unsigned int u32;
typedef unsigned long long u64;
typedef short s16x8 __attribute__((ext_vector_type(8)));
typedef float f32x4 __attribute__((ext_vector_type(4)));
typedef __bf16 bf16x2 __attribute__((ext_vector_type(2)));

#define BTH 2097152  // 16*512*256

__device__ __forceinline__ u16 f2bf(float f) {
  u32 u = __float_as_uint(f);
  u32 r = (u + 0x7FFFu + ((u >> 16) & 1u)) >> 16;  // RNE
  return (u16)r;
}
__device__ __forceinline__ float bf2f(u16 u) {
  return __uint_as_float(((u32)u) << 16);
}
__device__ __forceinline__ float sigm_(float x) { return 1.f / (1.f + __expf(-x)); }
__device__ __forceinline__ float tanh_(float x) {
  x = fminf(15.f, fmaxf(-15.f, x));
  float e = __expf(2.f * x);
  return (e - 1.f) / (e + 1.f);
}

#if defined(__has_builtin)
#if __has_builtin(__builtin_amdgcn_fdot2_f32_bf16)
#define HAVE_BF16_DOT2 1
#endif
#endif

// acc += dot(bf16x2(a), bf16x2(b))
__device__ __forceinline__ float dotp(u32 a, u32 b, float acc) {
#ifdef HAVE_BF16_DOT2
  return __builtin_amdgcn_fdot2_f32_bf16(__builtin_bit_cast(bf16x2, a),
                                         __builtin_bit_cast(bf16x2, b), acc, false);
#else
  acc += bf2f((u16)(a & 0xFFFFu)) * bf2f((u16)(b & 0xFFFFu));
  acc += bf2f((u16)(a >> 16)) * bf2f((u16)(b >> 16));
  return acc;
#endif
}

__device__ __forceinline__ void async_cp16(const u16* g, u16* l) {
  __builtin_amdgcn_global_load_lds(
      (const __attribute__((address_space(1))) void*)g,
      (__attribute__((address_space(3))) void*)l, 16, 0, 0);
}

// x [b][t][d] f32 -> xb [(t*16+b)][d] bf16
__global__ void cast_x_kernel(const float* __restrict__ x, u16* __restrict__ xb) {
  int e = blockIdx.x * 256 + threadIdx.x;  // < 2097152
  int d = e & 255;
  int r = e >> 8;  // b*512 + t
  int bb = r >> 9, t = r & 511;
  xb[(size_t)((t << 4) | bb) * 256 + d] = f2bf(x[e]);
}

__global__ void cast_w_kernel(const float* __restrict__ w, u16* __restrict__ o, int n) {
  int e = blockIdx.x * 256 + threadIdx.x;
  if (e < n) o[e] = f2bf(w[e]);
}

// B_w [o][d][h] f32 -> Btt [(o*256+h)][d] bf16  (n-major for GEMM B-operand)
__global__ void transpose_b_kernel(const float* __restrict__ Bw, u16* __restrict__ Btt) {
  __shared__ float T[64][65];
  const int o = blockIdx.y;
  const int d0 = (blockIdx.x >> 2) * 64;
  const int h0 = (blockIdx.x & 3) * 64;
  const int tid = threadIdx.x;
  const float* src = Bw + (size_t)o * 65536;
#pragma unroll
  for (int k = 0; k < 16; ++k) {
    int idx = tid + k * 256;
    int rr = idx >> 6, cc = idx & 63;
    T[rr][cc] = src[(size_t)(d0 + rr) * 256 + h0 + cc];
  }
  __syncthreads();
#pragma unroll
  for (int k = 0; k < 16; ++k) {
    int idx = tid + k * 256;
    int rr = idx >> 6, cc = idx & 63;
    Btt[(size_t)(o * 256 + h0 + rr) * 256 + d0 + cc] = f2bf(T[cc][rr]);
  }
}

// C[m][n] = A[m][:] . Bm[n][:]   (A,Bm bf16 row-major over K=256; fp32 accum)
template <bool OF32>
__global__ __launch_bounds__(256) void gemm_nt(
    const u16* __restrict__ A, const u16* __restrict__ Bm,
    u16* __restrict__ Cb, float* __restrict__ Cf, int N,
    const float* __restrict__ bias0, const float* __restrict__ bias1) {
  __shared__ u16 As[128 * 32];  // 8 KB, unpadded (global_load_lds layout)
  __shared__ u16 Bs[128 * 32];
  const int tid = threadIdx.x;
  const int m0 = blockIdx.x * 128;
  const int n0 = blockIdx.y * 128;
  const int wave = tid >> 6, lane = tid & 63;
  const int wm = (wave >> 1) * 64, wn = (wave & 1) * 64;
  const int qm = lane & 15, quad = lane >> 4;
  f32x4 acc[4][4] = {};
  const int c0 = tid, c1 = tid + 256;  // 512 chunks of 16 B per 8 KB tile
  const size_t ga0 = (size_t)(m0 + (c0 >> 2)) * 256 + (c0 & 3) * 8;
  const size_t ga1 = (size_t)(m0 + (c1 >> 2)) * 256 + (c1 & 3) * 8;
  const size_t gb0 = (size_t)(n0 + (c0 >> 2)) * 256 + (c0 & 3) * 8;
  const size_t gb1 = (size_t)(n0 + (c1 >> 2)) * 256 + (c1 & 3) * 8;

  for (int k0 = 0; k0 < 256; k0 += 32) {
    __syncthreads();  // prev-iter LDS reads done
    async_cp16(A + ga0 + k0, As + c0 * 8);
    async_cp16(A + ga1 + k0, As + c1 * 8);
    async_cp16(Bm + gb0 + k0, Bs + c0 * 8);
    async_cp16(Bm + gb1 + k0, Bs + c1 * 8);
    __syncthreads();  // vmcnt drained -> LDS valid
    s16x8 af[4], bfr[4];
#pragma unroll
    for (int i = 0; i < 4; ++i)
      af[i] = *(const s16x8*)&As[(wm + i * 16 + qm) * 32 + quad * 8];
#pragma unroll
    for (int j = 0; j < 4; ++j)
      bfr[j] = *(const s16x8*)&Bs[(wn + j * 16 + qm) * 32 + quad * 8];
#pragma unroll
    for (int i = 0; i < 4; ++i)
#pragma unroll
      for (int j = 0; j < 4; ++j)
        acc[i][j] = __builtin_amdgcn_mfma_f32_16x16x32_bf16(af[i], bfr[j], acc[i][j], 0, 0, 0);
  }
#pragma unroll
  for (int i = 0; i < 4; ++i) {
    int rg = m0 + wm + i * 16 + quad * 4;  // C/D: row = quad*4+reg, col = lane&15
#pragma unroll
    for (int j = 0; j < 4; ++j) {
      int cg = n0 + wn + j * 16 + qm;
      float bias = 0.f;
      if (OF32) bias = bias0[cg] + bias1[cg];
#pragma unroll
      for (int r = 0; r < 4; ++r) {
        float v = acc[i][j][r] + bias;
        size_t idx = (size_t)(rg + r) * (size_t)N + cg;
        if (OF32) Cf[idx] = v; else Cb[idx] = f2bf(v);
      }
    }
  }
}

// Persistent-chunk scan: 64 blocks = 16 batches x 4 o-slices of 64.
// Cross-block h exchange is SELF-VALIDATING 64-bit words: each relaxed
// agent-scope u64 atomic packs (tag=t+1)<<32 | bf16x2 h-pair. Consumer polls
// its 16 data words directly until all carry tag==t -> ONE coherence-point
// round trip per step instead of three (store-drain + tag publish + data
// load). Parity double-buffer + the per-batch all-to-all step dependency
// bounds skew to 1 step, so a slot is never overwritten before all its
// consumers read it. No __syncthreads in the loop: pure per-wave dataflow.
__global__ __launch_bounds__(512, 2) void scan_kernel(
    const u16* __restrict__ Y, const float* __restrict__ wx,
    const u16* __restrict__ Ubt, const float* __restrict__ Bb,
    float* cbuf, u64* hdata, float* __restrict__ out,
    int t0, int Tc) {
  const int tid = threadIdx.x;
  const int b = blockIdx.x >> 2;
  const int p = blockIdx.x & 3;
  const int obase = p << 6;
  const int oo = tid >> 3;   // 0..63
  const int s = tid & 7;     // K octant: k in [32s, 32s+32)
  const int o = obase + oo;
  const int myp = s >> 1;    // producer block of my k-slice
  const int half = s & 1;    // 16-word half within producer slice

  // U fragments: 4 gates x 4 uint4 (each uint4 = 8 bf16 over k)
  uint4 Ur[4][4];
  const uint4* Ub4 = (const uint4*)Ubt;
#pragma unroll
  for (int g = 0; g < 4; ++g) {
    int row = (g << 8) + o;
#pragma unroll
    for (int j = 0; j < 4; ++j) Ur[g][j] = Ub4[(size_t)row * 32 + s * 4 + j];
  }

  float c = cbuf[(b << 8) + o];
  const float bbias = Bb[o];

  const int tend = t0 + Tc;
  const u16* Yp = Y + (size_t)b * 65536 + (size_t)o * 256 + s * 32;
  uint4 Yc[4];
  {
    const uint4* y0 = (const uint4*)Yp;
    Yc[0] = y0[0]; Yc[1] = y0[1]; Yc[2] = y0[2]; Yc[3] = y0[3];
  }
  const float* wxp0 = wx + ((size_t)t0 * 16 + b) * 1024 + o;
  float w0 = wxp0[0], w1 = wxp0[256], w2 = wxp0[512], w3 = wxp0[768];
  float hn = 0.f;

  for (int t = t0; t < tend; ++t) {
    // prefetch next step's x-dependent data (fills during the h wait)
    int dn = (t + 1 < tend) ? (t + 1 - t0) : (t - t0);
    const uint4* ynp = (const uint4*)(Yp + (size_t)dn * 1048576);
    uint4 yn0 = ynp[0], yn1 = ynp[1], yn2 = ynp[2], yn3 = ynp[3];
    int tn = (t + 1 < tend) ? (t + 1) : t;
    const float* nwp = wx + ((size_t)tn * 16 + b) * 1024 + o;
    float nw0 = nwp[0], nw1 = nwp[256], nw2 = nwp[512], nw3 = nwp[768];

    // acquire h_t slice: poll the self-validating words until tag==t
    const int par = t & 1;
    u32 hd[16];
    {
      const u64* hp = hdata + ((((b << 1) + par) << 2) + myp) * 32 + (half << 4);
      u64 vv[16];
      u32 bad;
      do {
        bad = 0;
#pragma unroll
        for (int j = 0; j < 16; ++j)
          vv[j] = __hip_atomic_load(hp + j, __ATOMIC_RELAXED, __HIP_MEMORY_SCOPE_AGENT);
#pragma unroll
        for (int j = 0; j < 16; ++j)
          bad |= ((u32)(vv[j] >> 32)) ^ (u32)t;
      } while (bad != 0);
#pragma unroll
      for (int j = 0; j < 16; ++j) hd[j] = (u32)vv[j];
    }

    float a0 = 0.f, a1 = 0.f, a2 = 0.f, a3 = 0.f, am = 0.f;
#pragma unroll
    for (int j = 0; j < 4; ++j) {
      u32 h0 = hd[4 * j], h1 = hd[4 * j + 1], h2 = hd[4 * j + 2], h3 = hd[4 * j + 3];
      a0 = dotp(Ur[0][j].x, h0, a0); a0 = dotp(Ur[0][j].y, h1, a0);
      a0 = dotp(Ur[0][j].z, h2, a0); a0 = dotp(Ur[0][j].w, h3, a0);
      a1 = dotp(Ur[1][j].x, h0, a1); a1 = dotp(Ur[1][j].y, h1, a1);
      a1 = dotp(Ur[1][j].z, h2, a1); a1 = dotp(Ur[1][j].w, h3, a1);
      a2 = dotp(Ur[2][j].x, h0, a2); a2 = dotp(Ur[2][j].y, h1, a2);
      a2 = dotp(Ur[2][j].z, h2, a2); a2 = dotp(Ur[2][j].w, h3, a2);
      a3 = dotp(Ur[3][j].x, h0, a3); a3 = dotp(Ur[3][j].y, h1, a3);
      a3 = dotp(Ur[3][j].z, h2, a3); a3 = dotp(Ur[3][j].w, h3, a3);
      am = dotp(Yc[j].x, h0, am);   am = dotp(Yc[j].y, h1, am);
      am = dotp(Yc[j].z, h2, am);   am = dotp(Yc[j].w, h3, am);
    }
#pragma unroll
    for (int mk = 1; mk < 8; mk <<= 1) {
      a0 += __shfl_xor(a0, mk, 8);
      a1 += __shfl_xor(a1, mk, 8);
      a2 += __shfl_xor(a2, mk, 8);
      a3 += __shfl_xor(a3, mk, 8);
      am += __shfl_xor(am, mk, 8);
    }
    float gi = sigm_(a0 + w0);
    float gf = sigm_(a1 + w1);
    float go = sigm_(a2 + w2);
    float gg = tanh_(a3 + w3);
    float mm = tanh_(am + bbias);
    c = gf * c + gi * gg + 0.1f * mm;
    hn = go * tanh_(c);  // identical across the 8-lane cluster

    float hnext = __shfl_down(hn, 8);  // oo+1 cluster's hn (same wave)
    if (s == 0) {
      if (!(oo & 1)) {
        u32 pk = (u32)f2bf(hn) | ((u32)f2bf(hnext) << 16);
        u64 pk64 = ((u64)(u32)(t + 1) << 32) | (u64)pk;
        __hip_atomic_store(hdata + ((((b << 1) + ((t + 1) & 1)) << 2) + p) * 32 + (oo >> 1),
                           pk64, __ATOMIC_RELAXED, __HIP_MEMORY_SCOPE_AGENT);
      }
      out[((size_t)b * 512 + t) * 256 + o] = hn;
    }
    Yc[0] = yn0; Yc[1] = yn1; Yc[2] = yn2; Yc[3] = yn3;
    w0 = nw0; w1 = nw1; w2 = nw2; w3 = nw3;
  }
  if (s == 0) {
    cbuf[(b << 8) + o] = c;
    out[(size_t)BTH + (b << 8) + o] = hn;          // final h
    out[(size_t)BTH + 4096 + (b << 8) + o] = c;    // final c
  }
}

extern "C" void kernel_launch(void* const* d_in, const int* in_sizes, int n_in,
                              void* d_out, int out_size, void* d_ws, size_t ws_size,
                              hipStream_t stream) {
  const float* x  = (const float*)d_in[0];
  const float* Ww = (const float*)d_in[1];
  const float* Wb = (const float*)d_in[2];
  const float* Uw = (const float*)d_in[3];
  const float* Ub = (const float*)d_in[4];
  const float* Bw = (const float*)d_in[5];
  const float* Bb = (const float*)d_in[6];
  float* out = (float*)d_out;

  char* ws = (char*)d_ws;
  const size_t WX_B  = (size_t)512 * 16 * 1024 * 4;  // 33.5 MB
  const size_t XB_B  = (size_t)8192 * 256 * 2;       // 4.2 MB
  const size_t BTT_B = (size_t)65536 * 256 * 2;      // 33.5 MB
  const size_t WBT_B = (size_t)1024 * 256 * 2;       // 0.5 MB
  const size_t UBT_B = (size_t)1024 * 256 * 2;       // 0.5 MB
  const size_t CB_B  = 16384;                        // cbuf 16*256 f32
  const size_t HD_B  = 32768;                        // hdata 16*2*4*32 u64
  const size_t ST_B  = CB_B + HD_B;
  const size_t fixedB = WX_B + XB_B + BTT_B + WBT_B + UBT_B + ST_B;
  size_t avail = (ws_size > fixedB) ? (ws_size - fixedB) : 0;
  long Tc = (long)(avail / 2097152);  // Y bytes per timestep (bf16)
  if (Tc > 512) Tc = 512;
  Tc &= ~7L;
  if (Tc < 8) Tc = 8;

  u16* Y      = (u16*)ws;
  size_t YB   = (size_t)Tc * 2097152;
  float* wx   = (float*)(ws + YB);
  u16* xb     = (u16*)(ws + YB + WX_B);
  u16* Btt    = (u16*)(ws + YB + WX_B + XB_B);
  u16* Wbt    = (u16*)(ws + YB + WX_B + XB_B + BTT_B);
  u16* Ubt    = (u16*)(ws + YB + WX_B + XB_B + BTT_B + WBT_B);
  char* st    = ws + YB + WX_B + XB_B + BTT_B + WBT_B + UBT_B;
  float* cbuf = (float*)st;
  u64* hdata  = (u64*)(st + CB_B);

  hipMemsetAsync(st, 0, ST_B, stream);  // c0=0, h_0=0 with tag 0
  cast_x_kernel<<<8192, 256, 0, stream>>>(x, xb);
  cast_w_kernel<<<1024, 256, 0, stream>>>(Ww, Wbt, 262144);
  cast_w_kernel<<<1024, 256, 0, stream>>>(Uw, Ubt, 262144);
  transpose_b_kernel<<<dim3(16, 256), 256, 0, stream>>>(Bw, Btt);
  gemm_nt<true><<<dim3(64, 8), 256, 0, stream>>>(xb, Wbt, nullptr, wx, 1024, Wb, Ub);

  for (int t0 = 0; t0 < 512; t0 += (int)Tc) {
    int Tcur = (512 - t0 < (int)Tc) ? (512 - t0) : (int)Tc;
    gemm_nt<false><<<dim3(Tcur * 16 / 128, 512), 256, 0, stream>>>(
        xb + (size_t)t0 * 4096, Btt, Y, nullptr, 65536, nullptr, nullptr);
    scan_kernel<<<64, 512, 0, stream>>>(Y, wx, Ubt, Bb, cbuf, hdata, out, t0, Tcur);
  }
}

// Round 2
// 1705.289 us; speedup vs baseline: 2.6461x; 2.6461x over previous
//
#include <hip/hip_runtime.h>

typedef unsigned short u16;
typedef unsigned int u32;
typedef unsigned long long u64;
typedef short s16x8 __attribute__((ext_vector_type(8)));
typedef float f32x4 __attribute__((ext_vector_type(4)));
typedef __bf16 bf16x2 __attribute__((ext_vector_type(2)));

#define BTH 2097152  // 16*512*256

__device__ __forceinline__ u16 f2bf(float f) {
  u32 u = __float_as_uint(f);
  u32 r = (u + 0x7FFFu + ((u >> 16) & 1u)) >> 16;  // RNE
  return (u16)r;
}
__device__ __forceinline__ float bf2f(u16 u) {
  return __uint_as_float(((u32)u) << 16);
}
__device__ __forceinline__ float sigm_(float x) { return 1.f / (1.f + __expf(-x)); }
__device__ __forceinline__ float tanh_(float x) {
  x = fminf(15.f, fmaxf(-15.f, x));
  float e = __expf(2.f * x);
  return (e - 1.f) / (e + 1.f);
}

#if defined(__has_builtin)
#if __has_builtin(__builtin_amdgcn_fdot2_f32_bf16)
#define HAVE_BF16_DOT2 1
#endif
#endif

// acc += dot(bf16x2(a), bf16x2(b))
__device__ __forceinline__ float dotp(u32 a, u32 b, float acc) {
#ifdef HAVE_BF16_DOT2
  return __builtin_amdgcn_fdot2_f32_bf16(__builtin_bit_cast(bf16x2, a),
                                         __builtin_bit_cast(bf16x2, b), acc, false);
#else
  acc += bf2f((u16)(a & 0xFFFFu)) * bf2f((u16)(b & 0xFFFFu));
  acc += bf2f((u16)(a >> 16)) * bf2f((u16)(b >> 16));
  return acc;
#endif
}

__device__ __forceinline__ void async_cp16(const u16* g, u16* l) {
  __builtin_amdgcn_global_load_lds(
      (const __attribute__((address_space(1))) void*)g,
      (__attribute__((address_space(3))) void*)l, 16, 0, 0);
}

// x [b][t][d] f32 -> xb [(t*16+b)][d] bf16
__global__ void cast_x_kernel(const float* __restrict__ x, u16* __restrict__ xb) {
  int e = blockIdx.x * 256 + threadIdx.x;  // < 2097152
  int d = e & 255;
  int r = e >> 8;  // b*512 + t
  int bb = r >> 9, t = r & 511;
  xb[(size_t)((t << 4) | bb) * 256 + d] = f2bf(x[e]);
}

__global__ void cast_w_kernel(const float* __restrict__ w, u16* __restrict__ o, int n) {
  int e = blockIdx.x * 256 + threadIdx.x;
  if (e < n) o[e] = f2bf(w[e]);
}

// B_w [o][d][h] f32 -> Btt [(o*256+h)][d] bf16  (n-major for GEMM B-operand)
__global__ void transpose_b_kernel(const float* __restrict__ Bw, u16* __restrict__ Btt) {
  __shared__ float T[64][65];
  const int o = blockIdx.y;
  const int d0 = (blockIdx.x >> 2) * 64;
  const int h0 = (blockIdx.x & 3) * 64;
  const int tid = threadIdx.x;
  const float* src = Bw + (size_t)o * 65536;
#pragma unroll
  for (int k = 0; k < 16; ++k) {
    int idx = tid + k * 256;
    int rr = idx >> 6, cc = idx & 63;
    T[rr][cc] = src[(size_t)(d0 + rr) * 256 + h0 + cc];
  }
  __syncthreads();
#pragma unroll
  for (int k = 0; k < 16; ++k) {
    int idx = tid + k * 256;
    int rr = idx >> 6, cc = idx & 63;
    Btt[(size_t)(o * 256 + h0 + rr) * 256 + d0 + cc] = f2bf(T[cc][rr]);
  }
}

// C[m][n] = A[m][:] . Bm[n][:]   (A,Bm bf16 row-major over K=256; fp32 accum)
template <bool OF32>
__global__ __launch_bounds__(256) void gemm_nt(
    const u16* __restrict__ A, const u16* __restrict__ Bm,
    u16* __restrict__ Cb, float* __restrict__ Cf, int N,
    const float* __restrict__ bias0, const float* __restrict__ bias1) {
  __shared__ u16 As[128 * 32];  // 8 KB, unpadded (global_load_lds layout)
  __shared__ u16 Bs[128 * 32];
  const int tid = threadIdx.x;
  const int m0 = blockIdx.x * 128;
  const int n0 = blockIdx.y * 128;
  const int wave = tid >> 6, lane = tid & 63;
  const int wm = (wave >> 1) * 64, wn = (wave & 1) * 64;
  const int qm = lane & 15, quad = lane >> 4;
  f32x4 acc[4][4] = {};
  const int c0 = tid, c1 = tid + 256;  // 512 chunks of 16 B per 8 KB tile
  const size_t ga0 = (size_t)(m0 + (c0 >> 2)) * 256 + (c0 & 3) * 8;
  const size_t ga1 = (size_t)(m0 + (c1 >> 2)) * 256 + (c1 & 3) * 8;
  const size_t gb0 = (size_t)(n0 + (c0 >> 2)) * 256 + (c0 & 3) * 8;
  const size_t gb1 = (size_t)(n0 + (c1 >> 2)) * 256 + (c1 & 3) * 8;

  for (int k0 = 0; k0 < 256; k0 += 32) {
    __syncthreads();  // prev-iter LDS reads done
    async_cp16(A + ga0 + k0, As + c0 * 8);
    async_cp16(A + ga1 + k0, As + c1 * 8);
    async_cp16(Bm + gb0 + k0, Bs + c0 * 8);
    async_cp16(Bm + gb1 + k0, Bs + c1 * 8);
    __syncthreads();  // vmcnt drained -> LDS valid
    s16x8 af[4], bfr[4];
#pragma unroll
    for (int i = 0; i < 4; ++i)
      af[i] = *(const s16x8*)&As[(wm + i * 16 + qm) * 32 + quad * 8];
#pragma unroll
    for (int j = 0; j < 4; ++j)
      bfr[j] = *(const s16x8*)&Bs[(wn + j * 16 + qm) * 32 + quad * 8];
#pragma unroll
    for (int i = 0; i < 4; ++i)
#pragma unroll
      for (int j = 0; j < 4; ++j)
        acc[i][j] = __builtin_amdgcn_mfma_f32_16x16x32_bf16(af[i], bfr[j], acc[i][j], 0, 0, 0);
  }
#pragma unroll
  for (int i = 0; i < 4; ++i) {
    int rg = m0 + wm + i * 16 + quad * 4;  // C/D: row = quad*4+reg, col = lane&15
#pragma unroll
    for (int j = 0; j < 4; ++j) {
      int cg = n0 + wn + j * 16 + qm;
      float bias = 0.f;
      if (OF32) bias = bias0[cg] + bias1[cg];
#pragma unroll
      for (int r = 0; r < 4; ++r) {
        float v = acc[i][j][r] + bias;
        size_t idx = (size_t)(rg + r) * (size_t)N + cg;
        if (OF32) Cf[idx] = v; else Cb[idx] = f2bf(v);
      }
    }
  }
}

// Persistent-chunk scan: 64 blocks = 16 batches x 4 o-slices of 64.
// h exchange: producers store SELF-VALIDATING u64 words ((t+1)<<32 | bf16x2
// pair) with relaxed agent atomics -- no drain, no separate tag, no barrier.
// ONLY WAVE 0 of each block polls: 64 lanes x 2 words = all 128 words of
// h_t, cooperatively; exit when __all fresh. It then broadcasts the 512 B
// through LDS and releases an LDS flag that the other 7 waves spin on
// (bank-broadcast, zero fabric traffic). Poll fabric load: 64 waves x 1 KiB
// per sweep (~160 GB/s) -- BELOW the r0 tag-poll traffic, unlike the r1
// all-thread 16-word poll that congested the coherence point (10 TB/s).
// Skew bound: block P stores t+2 words only after computing t+1, which
// needs tag-(t+1) words from all 4 blocks, which needs every block's waves
// (incl. stragglers) done with step t -> parity double-buffer (global+LDS)
// is sufficient; wave0 can't overwrite lh[par] before stragglers read it.
__global__ __launch_bounds__(512, 2) void scan_kernel(
    const u16* __restrict__ Y, const float* __restrict__ wx,
    const u16* __restrict__ Ubt, const float* __restrict__ Bb,
    float* cbuf, u64* hdata, float* __restrict__ out,
    int t0, int Tc) {
  __shared__ u32 lh[2][128];
  __shared__ int lflag[2];
  const int tid = threadIdx.x;
  const int b = blockIdx.x >> 2;
  const int p = blockIdx.x & 3;
  const int oo = tid >> 3;   // 0..63
  const int s = tid & 7;     // K octant: k in [32s, 32s+32)
  const int o = (p << 6) + oo;
  const int wave = tid >> 6;
  const int lane = tid & 63;

  // U fragments: 4 gates x 4 uint4 (each uint4 = 8 bf16 over k)
  uint4 Ur[4][4];
  const uint4* Ub4 = (const uint4*)Ubt;
#pragma unroll
  for (int g = 0; g < 4; ++g) {
    int row = (g << 8) + o;
#pragma unroll
    for (int j = 0; j < 4; ++j) Ur[g][j] = Ub4[(size_t)row * 32 + s * 4 + j];
  }

  float c = cbuf[(b << 8) + o];
  const float bbias = Bb[o];
  if (tid < 2) lflag[tid] = t0 - 1;

  const int tend = t0 + Tc;
  const u16* Yp = Y + (size_t)b * 65536 + (size_t)o * 256 + s * 32;
  uint4 Yc[4];
  {
    const uint4* y0 = (const uint4*)Yp;
    Yc[0] = y0[0]; Yc[1] = y0[1]; Yc[2] = y0[2]; Yc[3] = y0[3];
  }
  const float* wxp0 = wx + ((size_t)t0 * 16 + b) * 1024 + o;
  float w0 = wxp0[0], w1 = wxp0[256], w2 = wxp0[512], w3 = wxp0[768];
  float hn = 0.f;
  u64* hg = hdata + ((size_t)b << 8);  // [par][128] u64 words per batch
  __syncthreads();  // lflag init visible

  for (int t = t0; t < tend; ++t) {
    // prefetch next step's x-dependent data (fills during the h wait)
    int dn = (t + 1 < tend) ? (t + 1 - t0) : (t - t0);
    const uint4* ynp = (const uint4*)(Yp + (size_t)dn * 1048576);
    uint4 yn0 = ynp[0], yn1 = ynp[1], yn2 = ynp[2], yn3 = ynp[3];
    int tn = (t + 1 < tend) ? (t + 1) : t;
    const float* nwp = wx + ((size_t)tn * 16 + b) * 1024 + o;
    float nw0 = nwp[0], nw1 = nwp[256], nw2 = nwp[512], nw3 = nwp[768];

    const int par = t & 1;
    if (wave == 0) {
      // cooperative poll: lane covers words 2*lane, 2*lane+1
      const u64* hp = hg + (par << 7) + (lane << 1);
      u64 v0, v1;
      for (;;) {
        v0 = __hip_atomic_load(hp, __ATOMIC_RELAXED, __HIP_MEMORY_SCOPE_AGENT);
        v1 = __hip_atomic_load(hp + 1, __ATOMIC_RELAXED, __HIP_MEMORY_SCOPE_AGENT);
        int ok = ((u32)(v0 >> 32) == (u32)t) & ((u32)(v1 >> 32) == (u32)t);
        if (__all(ok)) break;
      }
      lh[par][(lane << 1)] = (u32)v0;
      lh[par][(lane << 1) + 1] = (u32)v1;
      __hip_atomic_store(&lflag[par], t, __ATOMIC_RELEASE, __HIP_MEMORY_SCOPE_WORKGROUP);
    } else {
      while (__hip_atomic_load(&lflag[par], __ATOMIC_ACQUIRE, __HIP_MEMORY_SCOPE_WORKGROUP) < t) {}
    }

    // my 16 h-words (k slice [32s,32s+32)) from LDS
    uint4 hq[4];
    {
      const uint4* lp = (const uint4*)&lh[par][s << 4];
      hq[0] = lp[0]; hq[1] = lp[1]; hq[2] = lp[2]; hq[3] = lp[3];
    }

    float a0 = 0.f, a1 = 0.f, a2 = 0.f, a3 = 0.f, am = 0.f;
#pragma unroll
    for (int j = 0; j < 4; ++j) {
      u32 h0 = hq[j].x, h1 = hq[j].y, h2 = hq[j].z, h3 = hq[j].w;
      a0 = dotp(Ur[0][j].x, h0, a0); a0 = dotp(Ur[0][j].y, h1, a0);
      a0 = dotp(Ur[0][j].z, h2, a0); a0 = dotp(Ur[0][j].w, h3, a0);
      a1 = dotp(Ur[1][j].x, h0, a1); a1 = dotp(Ur[1][j].y, h1, a1);
      a1 = dotp(Ur[1][j].z, h2, a1); a1 = dotp(Ur[1][j].w, h3, a1);
      a2 = dotp(Ur[2][j].x, h0, a2); a2 = dotp(Ur[2][j].y, h1, a2);
      a2 = dotp(Ur[2][j].z, h2, a2); a2 = dotp(Ur[2][j].w, h3, a2);
      a3 = dotp(Ur[3][j].x, h0, a3); a3 = dotp(Ur[3][j].y, h1, a3);
      a3 = dotp(Ur[3][j].z, h2, a3); a3 = dotp(Ur[3][j].w, h3, a3);
      am = dotp(Yc[j].x, h0, am);   am = dotp(Yc[j].y, h1, am);
      am = dotp(Yc[j].z, h2, am);   am = dotp(Yc[j].w, h3, am);
    }
#pragma unroll
    for (int mk = 1; mk < 8; mk <<= 1) {
      a0 += __shfl_xor(a0, mk, 8);
      a1 += __shfl_xor(a1, mk, 8);
      a2 += __shfl_xor(a2, mk, 8);
      a3 += __shfl_xor(a3, mk, 8);
      am += __shfl_xor(am, mk, 8);
    }
    float gi = sigm_(a0 + w0);
    float gf = sigm_(a1 + w1);
    float go = sigm_(a2 + w2);
    float gg = tanh_(a3 + w3);
    float mm = tanh_(am + bbias);
    c = gf * c + gi * gg + 0.1f * mm;
    hn = go * tanh_(c);  // identical across the 8-lane cluster

    float hnext = __shfl_down(hn, 8);  // oo+1 cluster's hn (same wave)
    if (s == 0) {
      if (!(oo & 1)) {
        u32 pk = (u32)f2bf(hn) | ((u32)f2bf(hnext) << 16);
        u64 pk64 = ((u64)(u32)(t + 1) << 32) | (u64)pk;
        __hip_atomic_store(hg + (((size_t)((t + 1) & 1)) << 7) + (p << 5) + (oo >> 1),
                           pk64, __ATOMIC_RELAXED, __HIP_MEMORY_SCOPE_AGENT);
      }
      out[((size_t)b * 512 + t) * 256 + o] = hn;
    }
    Yc[0] = yn0; Yc[1] = yn1; Yc[2] = yn2; Yc[3] = yn3;
    w0 = nw0; w1 = nw1; w2 = nw2; w3 = nw3;
  }
  if (s == 0) {
    cbuf[(b << 8) + o] = c;
    out[(size_t)BTH + (b << 8) + o] = hn;          // final h
    out[(size_t)BTH + 4096 + (b << 8) + o] = c;    // final c
  }
}

extern "C" void kernel_launch(void* const* d_in, const int* in_sizes, int n_in,
                              void* d_out, int out_size, void* d_ws, size_t ws_size,
                              hipStream_t stream) {
  const float* x  = (const float*)d_in[0];
  const float* Ww = (const float*)d_in[1];
  const float* Wb = (const float*)d_in[2];
  const float* Uw = (const float*)d_in[3];
  const float* Ub = (const float*)d_in[4];
  const float* Bw = (const float*)d_in[5];
  const float* Bb = (const float*)d_in[6];
  float* out = (float*)d_out;

  char* ws = (char*)d_ws;
  const size_t WX_B  = (size_t)512 * 16 * 1024 * 4;  // 33.5 MB
  const size_t XB_B  = (size_t)8192 * 256 * 2;       // 4.2 MB
  const size_t BTT_B = (size_t)65536 * 256 * 2;      // 33.5 MB
  const size_t WBT_B = (size_t)1024 * 256 * 2;       // 0.5 MB
  const size_t UBT_B = (size_t)1024 * 256 * 2;       // 0.5 MB
  const size_t CB_B  = 16384;                        // cbuf 16*256 f32
  const size_t HD_B  = 32768;                        // hdata 16*2*128 u64
  const size_t ST_B  = CB_B + HD_B;
  const size_t fixedB = WX_B + XB_B + BTT_B + WBT_B + UBT_B + ST_B;
  size_t avail = (ws_size > fixedB) ? (ws_size - fixedB) : 0;
  long Tc = (long)(avail / 2097152);  // Y bytes per timestep (bf16)
  if (Tc > 512) Tc = 512;
  Tc &= ~7L;
  if (Tc < 8) Tc = 8;

  u16* Y      = (u16*)ws;
  size_t YB   = (size_t)Tc * 2097152;
  float* wx   = (float*)(ws + YB);
  u16* xb     = (u16*)(ws + YB + WX_B);
  u16* Btt    = (u16*)(ws + YB + WX_B + XB_B);
  u16* Wbt    = (u16*)(ws + YB + WX_B + XB_B + BTT_B);
  u16* Ubt    = (u16*)(ws + YB + WX_B + XB_B + BTT_B + WBT_B);
  char* st    = ws + YB + WX_B + XB_B + BTT_B + WBT_B + UBT_B;
  float* cbuf = (float*)st;
  u64* hdata  = (u64*)(st + CB_B);

  hipMemsetAsync(st, 0, ST_B, stream);  // c0=0, h_0=0 with tag 0
  cast_x_kernel<<<8192, 256, 0, stream>>>(x, xb);
  cast_w_kernel<<<1024, 256, 0, stream>>>(Ww, Wbt, 262144);
  cast_w_kernel<<<1024, 256, 0, stream>>>(Uw, Ubt, 262144);
  transpose_b_kernel<<<dim3(16, 256), 256, 0, stream>>>(Bw, Btt);
  gemm_nt<true><<<dim3(64, 8), 256, 0, stream>>>(xb, Wbt, nullptr, wx, 1024, Wb, Ub);

  for (int t0 = 0; t0 < 512; t0 += (int)Tc) {
    int Tcur = (512 - t0 < (int)Tc) ? (512 - t0) : (int)Tc;
    gemm_nt<false><<<dim3(Tcur * 16 / 128, 512), 256, 0, stream>>>(
        xb + (size_t)t0 * 4096, Btt, Y, nullptr, 65536, nullptr, nullptr);
    scan_kernel<<<64, 512, 0, stream>>>(Y, wx, Ubt, Bb, cbuf, hdata, out, t0, Tcur);
  }
}

// Round 3
// 1364.436 us; speedup vs baseline: 3.3071x; 1.2498x over previous
//
#include <hip/hip_runtime.h>

typedef unsigned short u16;
typedef unsigned int u32;
typedef unsigned long long u64;
typedef short s16x8 __attribute__((ext_vector_type(8)));
typedef float f32x4 __attribute__((ext_vector_type(4)));
typedef __bf16 bf16x2 __attribute__((ext_vector_type(2)));

#define BTH 2097152  // 16*512*256

__device__ __forceinline__ u16 f2bf(float f) {
  u32 u = __float_as_uint(f);
  u32 r = (u + 0x7FFFu + ((u >> 16) & 1u)) >> 16;  // RNE
  return (u16)r;
}
__device__ __forceinline__ float bf2f(u16 u) {
  return __uint_as_float(((u32)u) << 16);
}
__device__ __forceinline__ float sigm_(float x) { return 1.f / (1.f + __expf(-x)); }
__device__ __forceinline__ float tanh_(float x) {
  x = fminf(15.f, fmaxf(-15.f, x));
  float e = __expf(2.f * x);
  return (e - 1.f) / (e + 1.f);
}

#if defined(__has_builtin)
#if __has_builtin(__builtin_amdgcn_fdot2_f32_bf16)
#define HAVE_BF16_DOT2 1
#endif
#endif

// acc += dot(bf16x2(a), bf16x2(b))
__device__ __forceinline__ float dotp(u32 a, u32 b, float acc) {
#ifdef HAVE_BF16_DOT2
  return __builtin_amdgcn_fdot2_f32_bf16(__builtin_bit_cast(bf16x2, a),
                                         __builtin_bit_cast(bf16x2, b), acc, false);
#else
  acc += bf2f((u16)(a & 0xFFFFu)) * bf2f((u16)(b & 0xFFFFu));
  acc += bf2f((u16)(a >> 16)) * bf2f((u16)(b >> 16));
  return acc;
#endif
}

__device__ __forceinline__ void async_cp16(const u16* g, u16* l) {
  __builtin_amdgcn_global_load_lds(
      (const __attribute__((address_space(1))) void*)g,
      (__attribute__((address_space(3))) void*)l, 16, 0, 0);
}

// x [b][t][d] f32 -> xb [(t*16+b)][d] bf16
__global__ void cast_x_kernel(const float* __restrict__ x, u16* __restrict__ xb) {
  int e = blockIdx.x * 256 + threadIdx.x;  // < 2097152
  int d = e & 255;
  int r = e >> 8;  // b*512 + t
  int bb = r >> 9, t = r & 511;
  xb[(size_t)((t << 4) | bb) * 256 + d] = f2bf(x[e]);
}

__global__ void cast_w_kernel(const float* __restrict__ w, u16* __restrict__ o, int n) {
  int e = blockIdx.x * 256 + threadIdx.x;
  if (e < n) o[e] = f2bf(w[e]);
}

// B_w [o][d][h] f32 -> Btt [(o*256+h)][d] bf16  (n-major for GEMM B-operand)
__global__ void transpose_b_kernel(const float* __restrict__ Bw, u16* __restrict__ Btt) {
  __shared__ float T[64][65];
  const int o = blockIdx.y;
  const int d0 = (blockIdx.x >> 2) * 64;
  const int h0 = (blockIdx.x & 3) * 64;
  const int tid = threadIdx.x;
  const float* src = Bw + (size_t)o * 65536;
#pragma unroll
  for (int k = 0; k < 16; ++k) {
    int idx = tid + k * 256;
    int rr = idx >> 6, cc = idx & 63;
    T[rr][cc] = src[(size_t)(d0 + rr) * 256 + h0 + cc];
  }
  __syncthreads();
#pragma unroll
  for (int k = 0; k < 16; ++k) {
    int idx = tid + k * 256;
    int rr = idx >> 6, cc = idx & 63;
    Btt[(size_t)(o * 256 + h0 + rr) * 256 + d0 + cc] = f2bf(T[cc][rr]);
  }
}

// wx GEMM: C[m][n] = A[m][:] . Bm[n][:] + bias (f32 out, N=1024)
__global__ __launch_bounds__(256) void gemm_wx(
    const u16* __restrict__ A, const u16* __restrict__ Bm,
    float* __restrict__ Cf, int N,
    const float* __restrict__ bias0, const float* __restrict__ bias1) {
  __shared__ u16 As[128 * 32];
  __shared__ u16 Bs[128 * 32];
  const int tid = threadIdx.x;
  const int m0 = blockIdx.x * 128;
  const int n0 = blockIdx.y * 128;
  const int wave = tid >> 6, lane = tid & 63;
  const int wm = (wave >> 1) * 64, wn = (wave & 1) * 64;
  const int qm = lane & 15, quad = lane >> 4;
  f32x4 acc[4][4] = {};
  const int c0 = tid, c1 = tid + 256;
  const size_t ga0 = (size_t)(m0 + (c0 >> 2)) * 256 + (c0 & 3) * 8;
  const size_t ga1 = (size_t)(m0 + (c1 >> 2)) * 256 + (c1 & 3) * 8;
  const size_t gb0 = (size_t)(n0 + (c0 >> 2)) * 256 + (c0 & 3) * 8;
  const size_t gb1 = (size_t)(n0 + (c1 >> 2)) * 256 + (c1 & 3) * 8;

  for (int k0 = 0; k0 < 256; k0 += 32) {
    __syncthreads();
    async_cp16(A + ga0 + k0, As + c0 * 8);
    async_cp16(A + ga1 + k0, As + c1 * 8);
    async_cp16(Bm + gb0 + k0, Bs + c0 * 8);
    async_cp16(Bm + gb1 + k0, Bs + c1 * 8);
    __syncthreads();
    s16x8 af[4], bfr[4];
#pragma unroll
    for (int i = 0; i < 4; ++i)
      af[i] = *(const s16x8*)&As[(wm + i * 16 + qm) * 32 + quad * 8];
#pragma unroll
    for (int j = 0; j < 4; ++j)
      bfr[j] = *(const s16x8*)&Bs[(wn + j * 16 + qm) * 32 + quad * 8];
#pragma unroll
    for (int i = 0; i < 4; ++i)
#pragma unroll
      for (int j = 0; j < 4; ++j)
        acc[i][j] = __builtin_amdgcn_mfma_f32_16x16x32_bf16(af[i], bfr[j], acc[i][j], 0, 0, 0);
  }
#pragma unroll
  for (int i = 0; i < 4; ++i) {
    int rg = m0 + wm + i * 16 + quad * 4;
#pragma unroll
    for (int j = 0; j < 4; ++j) {
      int cg = n0 + wn + j * 16 + qm;
      float bias = bias0[cg] + bias1[cg];
#pragma unroll
      for (int r = 0; r < 4; ++r)
        Cf[(size_t)(rg + r) * (size_t)N + cg] = acc[i][j][r] + bias;
    }
  }
}

// Fused pipeline kernel: blocks [0,sblocks) run the scan for chunk (t0,Tcur)
// reading Ysc; blocks [sblocks, sblocks+ng) run the Y-GEMM for the NEXT
// chunk into Ygm (128x256 tile, 512 threads, 8 waves 2x4). Dependency
// between a chunk's GEMM and its scan is enforced by launch boundaries
// (stream serialization); within a launch, scan c and gemm c+1 touch
// disjoint Y buffers. GEMM blocks never wait on anything, so even
// pathological dispatch order only degrades to serial execution, never
// deadlocks. LDS is a union: scan uses 1.5 KB, gemm 24 KB.
__global__ __launch_bounds__(512, 2) void fused_kernel(
    const u16* __restrict__ Ysc, const float* __restrict__ wx,
    const u16* __restrict__ Ubt, const float* __restrict__ Bb,
    float* cbuf, u64* hdata, float* __restrict__ out, int t0, int Tcur,
    const u16* __restrict__ Ag, const u16* __restrict__ Bg,
    u16* __restrict__ Ygm, int sblocks) {
  __shared__ __align__(16) char smem[24576];
  if ((int)blockIdx.x >= sblocks) {
    // ---------------- GEMM path: C[m][n] into Ygm (bf16, N=65536) --------
    u16* As = (u16*)smem;           // 128 x 32
    u16* Bs = (u16*)(smem + 8192);  // 256 x 32
    const int gb = (int)blockIdx.x - sblocks;
    const int mt = gb >> 8, nt = gb & 255;
    const int tid = threadIdx.x;
    const int m0 = mt * 128, n0 = nt * 256;
    const int wave = tid >> 6, lane = tid & 63;
    const int wm = (wave >> 2) * 64, wn = (wave & 3) * 64;
    const int qm = lane & 15, quad = lane >> 4;
    f32x4 acc[4][4] = {};
    const size_t ga = (size_t)(m0 + (tid >> 2)) * 256 + (tid & 3) * 8;
    const int c0 = tid, c1 = tid + 512;
    const size_t gb0 = (size_t)(n0 + (c0 >> 2)) * 256 + (c0 & 3) * 8;
    const size_t gb1 = (size_t)(n0 + (c1 >> 2)) * 256 + (c1 & 3) * 8;
    for (int k0 = 0; k0 < 256; k0 += 32) {
      __syncthreads();
      async_cp16(Ag + ga + k0, As + tid * 8);
      async_cp16(Bg + gb0 + k0, Bs + c0 * 8);
      async_cp16(Bg + gb1 + k0, Bs + c1 * 8);
      __syncthreads();
      s16x8 af[4], bfr[4];
#pragma unroll
      for (int i = 0; i < 4; ++i)
        af[i] = *(const s16x8*)&As[(wm + i * 16 + qm) * 32 + quad * 8];
#pragma unroll
      for (int j = 0; j < 4; ++j)
        bfr[j] = *(const s16x8*)&Bs[(wn + j * 16 + qm) * 32 + quad * 8];
#pragma unroll
      for (int i = 0; i < 4; ++i)
#pragma unroll
        for (int j = 0; j < 4; ++j)
          acc[i][j] = __builtin_amdgcn_mfma_f32_16x16x32_bf16(af[i], bfr[j], acc[i][j], 0, 0, 0);
    }
#pragma unroll
    for (int i = 0; i < 4; ++i) {
      int rg = m0 + wm + i * 16 + quad * 4;
#pragma unroll
      for (int j = 0; j < 4; ++j) {
        int cg = n0 + wn + j * 16 + qm;
#pragma unroll
        for (int r = 0; r < 4; ++r)
          Ygm[(size_t)(rg + r) * 65536 + cg] = f2bf(acc[i][j][r]);
      }
    }
    return;
  }
  // ---------------- scan path (identical protocol to r2) ----------------
  u32(*lh)[128] = (u32(*)[128])smem;
  int* lflag = (int*)(smem + 1024);
  const int tid = threadIdx.x;
  const int b = blockIdx.x >> 2;
  const int p = blockIdx.x & 3;
  const int oo = tid >> 3;  // 0..63
  const int s = tid & 7;    // K octant: k in [32s, 32s+32)
  const int o = (p << 6) + oo;
  const int wave = tid >> 6;
  const int lane = tid & 63;

  uint4 Ur[4][4];
  const uint4* Ub4 = (const uint4*)Ubt;
#pragma unroll
  for (int g = 0; g < 4; ++g) {
    int row = (g << 8) + o;
#pragma unroll
    for (int j = 0; j < 4; ++j) Ur[g][j] = Ub4[(size_t)row * 32 + s * 4 + j];
  }

  float c = cbuf[(b << 8) + o];
  const float bbias = Bb[o];
  if (tid < 2) lflag[tid] = t0 - 1;

  const int tend = t0 + Tcur;
  const u16* Yp = Ysc + (size_t)b * 65536 + (size_t)o * 256 + s * 32;
  uint4 Yc[4];
  {
    const uint4* y0 = (const uint4*)Yp;
    Yc[0] = y0[0]; Yc[1] = y0[1]; Yc[2] = y0[2]; Yc[3] = y0[3];
  }
  const float* wxp0 = wx + ((size_t)t0 * 16 + b) * 1024 + o;
  float w0 = wxp0[0], w1 = wxp0[256], w2 = wxp0[512], w3 = wxp0[768];
  float hn = 0.f;
  u64* hg = hdata + ((size_t)b << 8);  // [par][128] u64 words per batch
  __syncthreads();  // lflag init visible

  for (int t = t0; t < tend; ++t) {
    // prefetch next step's x-dependent data (fills during the h wait)
    int dn = (t + 1 < tend) ? (t + 1 - t0) : (t - t0);
    const uint4* ynp = (const uint4*)(Yp + (size_t)dn * 1048576);
    uint4 yn0 = ynp[0], yn1 = ynp[1], yn2 = ynp[2], yn3 = ynp[3];
    int tn = (t + 1 < tend) ? (t + 1) : t;
    const float* nwp = wx + ((size_t)tn * 16 + b) * 1024 + o;
    float nw0 = nwp[0], nw1 = nwp[256], nw2 = nwp[512], nw3 = nwp[768];

    const int par = t & 1;
    if (wave == 0) {
      const u64* hp = hg + (par << 7) + (lane << 1);
      u64 v0, v1;
      for (;;) {
        v0 = __hip_atomic_load(hp, __ATOMIC_RELAXED, __HIP_MEMORY_SCOPE_AGENT);
        v1 = __hip_atomic_load(hp + 1, __ATOMIC_RELAXED, __HIP_MEMORY_SCOPE_AGENT);
        int ok = ((u32)(v0 >> 32) == (u32)t) & ((u32)(v1 >> 32) == (u32)t);
        if (__all(ok)) break;
      }
      lh[par][(lane << 1)] = (u32)v0;
      lh[par][(lane << 1) + 1] = (u32)v1;
      __hip_atomic_store(&lflag[par], t, __ATOMIC_RELEASE, __HIP_MEMORY_SCOPE_WORKGROUP);
    } else {
      while (__hip_atomic_load(&lflag[par], __ATOMIC_ACQUIRE, __HIP_MEMORY_SCOPE_WORKGROUP) < t) {}
    }

    uint4 hq[4];
    {
      const uint4* lp = (const uint4*)&lh[par][s << 4];
      hq[0] = lp[0]; hq[1] = lp[1]; hq[2] = lp[2]; hq[3] = lp[3];
    }

    float a0 = 0.f, a1 = 0.f, a2 = 0.f, a3 = 0.f, am = 0.f;
#pragma unroll
    for (int j = 0; j < 4; ++j) {
      u32 h0 = hq[j].x, h1 = hq[j].y, h2 = hq[j].z, h3 = hq[j].w;
      a0 = dotp(Ur[0][j].x, h0, a0); a0 = dotp(Ur[0][j].y, h1, a0);
      a0 = dotp(Ur[0][j].z, h2, a0); a0 = dotp(Ur[0][j].w, h3, a0);
      a1 = dotp(Ur[1][j].x, h0, a1); a1 = dotp(Ur[1][j].y, h1, a1);
      a1 = dotp(Ur[1][j].z, h2, a1); a1 = dotp(Ur[1][j].w, h3, a1);
      a2 = dotp(Ur[2][j].x, h0, a2); a2 = dotp(Ur[2][j].y, h1, a2);
      a2 = dotp(Ur[2][j].z, h2, a2); a2 = dotp(Ur[2][j].w, h3, a2);
      a3 = dotp(Ur[3][j].x, h0, a3); a3 = dotp(Ur[3][j].y, h1, a3);
      a3 = dotp(Ur[3][j].z, h2, a3); a3 = dotp(Ur[3][j].w, h3, a3);
      am = dotp(Yc[j].x, h0, am);   am = dotp(Yc[j].y, h1, am);
      am = dotp(Yc[j].z, h2, am);   am = dotp(Yc[j].w, h3, am);
    }
#pragma unroll
    for (int mk = 1; mk < 8; mk <<= 1) {
      a0 += __shfl_xor(a0, mk, 8);
      a1 += __shfl_xor(a1, mk, 8);
      a2 += __shfl_xor(a2, mk, 8);
      a3 += __shfl_xor(a3, mk, 8);
      am += __shfl_xor(am, mk, 8);
    }
    float gi = sigm_(a0 + w0);
    float gf = sigm_(a1 + w1);
    float go = sigm_(a2 + w2);
    float gg = tanh_(a3 + w3);
    float mm = tanh_(am + bbias);
    c = gf * c + gi * gg + 0.1f * mm;
    hn = go * tanh_(c);  // identical across the 8-lane cluster

    float hnext = __shfl_down(hn, 8);  // oo+1 cluster's hn (same wave)
    if (s == 0) {
      if (!(oo & 1)) {
        u32 pk = (u32)f2bf(hn) | ((u32)f2bf(hnext) << 16);
        u64 pk64 = ((u64)(u32)(t + 1) << 32) | (u64)pk;
        __hip_atomic_store(hg + (((size_t)((t + 1) & 1)) << 7) + (p << 5) + (oo >> 1),
                           pk64, __ATOMIC_RELAXED, __HIP_MEMORY_SCOPE_AGENT);
      }
      out[((size_t)b * 512 + t) * 256 + o] = hn;
    }
    Yc[0] = yn0; Yc[1] = yn1; Yc[2] = yn2; Yc[3] = yn3;
    w0 = nw0; w1 = nw1; w2 = nw2; w3 = nw3;
  }
  if (s == 0) {
    cbuf[(b << 8) + o] = c;
    out[(size_t)BTH + (b << 8) + o] = hn;          // final h
    out[(size_t)BTH + 4096 + (b << 8) + o] = c;    // final c
  }
}

extern "C" void kernel_launch(void* const* d_in, const int* in_sizes, int n_in,
                              void* d_out, int out_size, void* d_ws, size_t ws_size,
                              hipStream_t stream) {
  const float* x  = (const float*)d_in[0];
  const float* Ww = (const float*)d_in[1];
  const float* Wb = (const float*)d_in[2];
  const float* Uw = (const float*)d_in[3];
  const float* Ub = (const float*)d_in[4];
  const float* Bw = (const float*)d_in[5];
  const float* Bb = (const float*)d_in[6];
  float* out = (float*)d_out;

  char* ws = (char*)d_ws;
  const size_t WX_B  = (size_t)512 * 16 * 1024 * 4;  // 33.5 MB
  const size_t XB_B  = (size_t)8192 * 256 * 2;       // 4.2 MB
  const size_t BTT_B = (size_t)65536 * 256 * 2;      // 33.5 MB
  const size_t WBT_B = (size_t)1024 * 256 * 2;       // 0.5 MB
  const size_t UBT_B = (size_t)1024 * 256 * 2;       // 0.5 MB
  const size_t CB_B  = 16384;                        // cbuf 16*256 f32
  const size_t HD_B  = 32768;                        // hdata 16*2*128 u64
  const size_t ST_B  = CB_B + HD_B;
  const size_t fixedB = WX_B + XB_B + BTT_B + WBT_B + UBT_B + ST_B;
  size_t avail = (ws_size > fixedB) ? (ws_size - fixedB) : 0;
  long Tc = (long)(avail / (2 * 2097152));  // two Y buffers (double-buffer)
  if (Tc > 64) Tc = 64;   // 64-step chunks: gemm0 exposure vs launch count
  Tc &= ~7L;
  if (Tc < 8) Tc = 8;

  size_t YB   = (size_t)Tc * 2097152;
  u16* Y0     = (u16*)ws;
  u16* Y1     = (u16*)(ws + YB);
  float* wx   = (float*)(ws + 2 * YB);
  u16* xb     = (u16*)(ws + 2 * YB + WX_B);
  u16* Btt    = (u16*)(ws + 2 * YB + WX_B + XB_B);
  u16* Wbt    = (u16*)(ws + 2 * YB + WX_B + XB_B + BTT_B);
  u16* Ubt    = (u16*)(ws + 2 * YB + WX_B + XB_B + BTT_B + WBT_B);
  char* st    = ws + 2 * YB + WX_B + XB_B + BTT_B + WBT_B + UBT_B;
  float* cbuf = (float*)st;
  u64* hdata  = (u64*)(st + CB_B);

  hipMemsetAsync(st, 0, ST_B, stream);  // c0=0, h_0=0 with tag 0
  cast_x_kernel<<<8192, 256, 0, stream>>>(x, xb);
  cast_w_kernel<<<1024, 256, 0, stream>>>(Ww, Wbt, 262144);
  cast_w_kernel<<<1024, 256, 0, stream>>>(Uw, Ubt, 262144);
  transpose_b_kernel<<<dim3(16, 256), 256, 0, stream>>>(Bw, Btt);
  gemm_wx<<<dim3(64, 8), 256, 0, stream>>>(xb, Wbt, wx, 1024, Wb, Ub);

  // GEMM for chunk 0 (exposed; nothing to overlap with)
  {
    int Tc0 = (512 < Tc) ? 512 : (int)Tc;
    int ng = (Tc0 * 16 / 128) * 256;
    fused_kernel<<<ng, 512, 0, stream>>>(nullptr, wx, Ubt, Bb, cbuf, hdata, out,
                                         0, 0, xb, Btt, Y0, 0);
  }
  int cidx = 0;
  for (int t0 = 0; t0 < 512; t0 += (int)Tc, ++cidx) {
    int Tcur = (512 - t0 < (int)Tc) ? (512 - t0) : (int)Tc;
    int t0n = t0 + Tcur;
    u16* Ysc = (cidx & 1) ? Y1 : Y0;
    int ng = 0;
    const u16* Ag = xb;
    u16* Ygm = (cidx & 1) ? Y0 : Y1;
    if (t0n < 512) {
      int Tcn = (512 - t0n < (int)Tc) ? (512 - t0n) : (int)Tc;
      ng = (Tcn * 16 / 128) * 256;
      Ag = xb + (size_t)t0n * 4096;
    }
    fused_kernel<<<64 + ng, 512, 0, stream>>>(Ysc, wx, Ubt, Bb, cbuf, hdata, out,
                                              t0, Tcur, Ag, Btt, Ygm, 64);
  }
}